// Round 9
// baseline (268.051 us; speedup 1.0000x reference)
//
#include <hip/hip_runtime.h>
#include <hip/hip_bf16.h>

// fp32 inputs (confirmed r2). Internal pipeline bf16 MFMA.
// Gen identity: w = exp2(max(e,0.2e)) = max(A_i*B_j, C_i*D_j).
// r9 = r8 + adj packed to 1-bit mask (L2-resident, 64MB->2MB HBM) +
//      V fragments direct from global w/ 1-iter register prefetch (no Vb LDS) +
//      denominator via P@ones MFMA (constant B-frag).

typedef unsigned short ushort_t;
typedef __attribute__((ext_vector_type(8))) short bf16x8;
typedef __attribute__((ext_vector_type(4))) float f32x4;

#define LOG2E 1.4426950408889634f

__device__ __forceinline__ ushort_t f2bf(float x) {
    unsigned u = __builtin_bit_cast(unsigned, x);
    u += 0x7FFFu + ((u >> 16) & 1u);   // RNE
    return (ushort_t)(u >> 16);
}

// ---------------- kernel 0: pack adj (int32 0/1) -> bitmask pk[i][jo*64+k] ----------
// byte pk[i*512 + jo*64 + k] holds bits e=0..7 for j = k*64 + jo*8 + e.
__global__ __launch_bounds__(256) void pack_adj(const int* __restrict__ adj,
                                                unsigned char* __restrict__ pk) {
    int wv = threadIdx.x >> 6, lane = threadIdx.x & 63;
    int row = blockIdx.x * 4 + wv;
    const int* ap = adj + (unsigned)row * 4096 + lane;
    unsigned char* pp = pk + (unsigned)row * 512;
    int jo = lane & 7;
#pragma unroll 2
    for (int k4 = 0; k4 < 16; k4++) {
        int v0 = ap[(k4 * 4 + 0) * 64];
        int v1 = ap[(k4 * 4 + 1) * 64];
        int v2 = ap[(k4 * 4 + 2) * 64];
        int v3 = ap[(k4 * 4 + 3) * 64];
        unsigned long long m0 = __ballot(v0 > 0);
        unsigned long long m1 = __ballot(v1 > 0);
        unsigned long long m2 = __ballot(v2 > 0);
        unsigned long long m3 = __ballot(v3 > 0);
        if (lane < 8) {
            int sh = jo * 8;
            unsigned b = ((unsigned)(m0 >> sh) & 0xFFu)
                       | (((unsigned)(m1 >> sh) & 0xFFu) << 8)
                       | (((unsigned)(m2 >> sh) & 0xFFu) << 16)
                       | (((unsigned)(m3 >> sh) & 0xFFu) << 24);
            *(unsigned*)(pp + jo * 64 + k4 * 4) = b;
        }
    }
}

// ---------------- kernel 1: WT[c][k] = W[k][c], 512x512, fp32 -> bf16 ----------------
__global__ __launch_bounds__(256) void transpose_w(const float* __restrict__ W,
                                                   ushort_t* __restrict__ WT) {
    __shared__ ushort_t t[32][33];
    int bx = blockIdx.x & 15, by = blockIdx.x >> 4;
    int tx = threadIdx.x & 31, ty = threadIdx.x >> 5;
#pragma unroll
    for (int i = 0; i < 32; i += 8)
        t[ty + i][tx] = f2bf(W[(by * 32 + ty + i) * 512 + bx * 32 + tx]);
    __syncthreads();
#pragma unroll
    for (int i = 0; i < 32; i += 8)
        WT[(bx * 32 + ty + i) * 512 + by * 32 + tx] = t[tx][ty + i];
}

// -------- kernel 2: WhT = WT @ h^T, pipelined (r8 proven) + exp epilogue --------
__global__ __launch_bounds__(256, 4) void gemm_whT(const ushort_t* __restrict__ WT,
                                                   const float* __restrict__ h,
                                                   const float* __restrict__ a,
                                                   ushort_t* __restrict__ WhT,
                                                   float* __restrict__ expA,
                                                   float* __restrict__ expC,
                                                   float* __restrict__ expB,
                                                   float* __restrict__ expD) {
    __shared__ __align__(16) ushort_t Al[2][64][72];
    __shared__ __align__(16) ushort_t Bl[2][64][72];
    __shared__ float asrc[64], adst[64];
    __shared__ float sred[2][4][64];
    int tid = threadIdx.x;
    int wave = tid >> 6, lane = tid & 63, quad = lane >> 4, nn = lane & 15;
    int mb = blockIdx.x & 7, nb = blockIdx.x >> 3;
    if (tid < 64) {
        asrc[tid] = a[tid] * LOG2E;
        adst[tid] = a[64 + tid] * LOG2E;
    }
    int r = tid >> 2, s0 = tid & 3;
    const ushort_t* Ag = WT + (unsigned)((mb * 64 + r) * 512 + s0 * 8);
    const float* Bg = h + (unsigned)((nb * 64 + r) * 512 + s0 * 8);
    bf16x8 pA0 = *(const bf16x8*)(Ag);
    bf16x8 pA1 = *(const bf16x8*)(Ag + 32);
    float4 pb0 = *(const float4*)(Bg);
    float4 pb1 = *(const float4*)(Bg + 4);
    float4 pb2 = *(const float4*)(Bg + 32);
    float4 pb3 = *(const float4*)(Bg + 36);
    f32x4 acc[4] = {};
#pragma unroll 2
    for (int t = 0; t < 8; t++) {
        int cb = t & 1;
        *(bf16x8*)&Al[cb][r][s0 * 8] = pA0;
        *(bf16x8*)&Al[cb][r][s0 * 8 + 32] = pA1;
        bf16x8 bv;
        bv[0] = (short)f2bf(pb0.x); bv[1] = (short)f2bf(pb0.y);
        bv[2] = (short)f2bf(pb0.z); bv[3] = (short)f2bf(pb0.w);
        bv[4] = (short)f2bf(pb1.x); bv[5] = (short)f2bf(pb1.y);
        bv[6] = (short)f2bf(pb1.z); bv[7] = (short)f2bf(pb1.w);
        *(bf16x8*)&Bl[cb][r][s0 * 8] = bv;
        bv[0] = (short)f2bf(pb2.x); bv[1] = (short)f2bf(pb2.y);
        bv[2] = (short)f2bf(pb2.z); bv[3] = (short)f2bf(pb2.w);
        bv[4] = (short)f2bf(pb3.x); bv[5] = (short)f2bf(pb3.y);
        bv[6] = (short)f2bf(pb3.z); bv[7] = (short)f2bf(pb3.w);
        *(bf16x8*)&Bl[cb][r][s0 * 8 + 32] = bv;
        if (t < 7) {
            int ko = (t + 1) * 64;
            pA0 = *(const bf16x8*)(Ag + ko);
            pA1 = *(const bf16x8*)(Ag + ko + 32);
            pb0 = *(const float4*)(Bg + ko);
            pb1 = *(const float4*)(Bg + ko + 4);
            pb2 = *(const float4*)(Bg + ko + 32);
            pb3 = *(const float4*)(Bg + ko + 36);
        }
        if (t > 0) {
            int pb = cb ^ 1;
            bf16x8 af0 = *(const bf16x8*)&Al[pb][wave * 16 + nn][quad * 8];
            bf16x8 af1 = *(const bf16x8*)&Al[pb][wave * 16 + nn][32 + quad * 8];
#pragma unroll
            for (int nt = 0; nt < 4; nt++) {
                bf16x8 b0 = *(const bf16x8*)&Bl[pb][nt * 16 + nn][quad * 8];
                bf16x8 b1 = *(const bf16x8*)&Bl[pb][nt * 16 + nn][32 + quad * 8];
                acc[nt] = __builtin_amdgcn_mfma_f32_16x16x32_bf16(af0, b0, acc[nt], 0, 0, 0);
                acc[nt] = __builtin_amdgcn_mfma_f32_16x16x32_bf16(af1, b1, acc[nt], 0, 0, 0);
            }
        }
        __syncthreads();
    }
    {
        bf16x8 af0 = *(const bf16x8*)&Al[1][wave * 16 + nn][quad * 8];
        bf16x8 af1 = *(const bf16x8*)&Al[1][wave * 16 + nn][32 + quad * 8];
#pragma unroll
        for (int nt = 0; nt < 4; nt++) {
            bf16x8 b0 = *(const bf16x8*)&Bl[1][nt * 16 + nn][quad * 8];
            bf16x8 b1 = *(const bf16x8*)&Bl[1][nt * 16 + nn][32 + quad * 8];
            acc[nt] = __builtin_amdgcn_mfma_f32_16x16x32_bf16(af0, b0, acc[nt], 0, 0, 0);
            acc[nt] = __builtin_amdgcn_mfma_f32_16x16x32_bf16(af1, b1, acc[nt], 0, 0, 0);
        }
    }
    int row0 = mb * 64 + wave * 16 + quad * 4;
    int col0 = nb * 64 + nn;
    int f0i = wave * 16 + quad * 4;
#pragma unroll
    for (int nt = 0; nt < 4; nt++) {
        float s = 0.f, d = 0.f;
#pragma unroll
        for (int rr = 0; rr < 4; rr++) {
            float v = acc[nt][rr];
            WhT[(unsigned)((row0 + rr) * 4096 + col0 + nt * 16)] = f2bf(v);
            s += v * asrc[f0i + rr];
            d += v * adst[f0i + rr];
        }
        s += __shfl_xor(s, 16); s += __shfl_xor(s, 32);
        d += __shfl_xor(d, 16); d += __shfl_xor(d, 32);
        if (quad == 0) { sred[0][wave][nt * 16 + nn] = s; sred[1][wave][nt * 16 + nn] = d; }
    }
    __syncthreads();
    if (tid < 64) {
        float s = sred[0][0][tid] + sred[0][1][tid] + sred[0][2][tid] + sred[0][3][tid];
        unsigned idx = mb * 4096 + nb * 64 + tid;
        expA[idx] = __builtin_amdgcn_exp2f(s);
        expC[idx] = __builtin_amdgcn_exp2f(0.2f * s);
    } else if (tid < 128) {
        int c = tid - 64;
        float d = sred[1][0][c] + sred[1][1][c] + sred[1][2][c] + sred[1][3][c];
        unsigned idx = mb * 4096 + nb * 64 + c;
        expB[idx] = __builtin_amdgcn_exp2f(d);
        expD[idx] = __builtin_amdgcn_exp2f(0.2f * d);
    }
}

// -------- kernel 3: fused masked-softmax attention + P@V + ELU --------
// 512 blocks x 512 thr (512,4). i-tile 32 x 2 heads; j-tile 64; P dbuf LDS,
// bottom barrier. V frags direct from global (1-iter reg prefetch, MFMA-read
// before slot overwrite). Denominator via P@ones MFMA. Mask from pk bits.
__global__ __launch_bounds__(512, 4) void gat_attn(const unsigned char* __restrict__ pk,
                                                   const ushort_t* __restrict__ WhT,
                                                   const float* __restrict__ expA,
                                                   const float* __restrict__ expC,
                                                   const float* __restrict__ expB,
                                                   const float* __restrict__ expD,
                                                   float* __restrict__ out) {
    __shared__ __align__(16) ushort_t Pb[2][2][32][72];   // 18432 B (cmb overlays)
    __shared__ float denomp[2][2][32];
    int tid = threadIdx.x;
    int wave = tid >> 6, lane = tid & 63, quad = lane >> 4, nn = lane & 15;
    int hb = blockIdx.x >> 7, ib = blockIdx.x & 127;   // adj row-band on one XCD
    int i0 = ib * 32;
    // gen role
    int hh = tid >> 8, tt = tid & 255;
    int pi = tt >> 3, jo = tt & 7;
    int head = hb * 2 + hh;
    float Ai = expA[head * 4096 + i0 + pi];
    float Ci = expC[head * 4096 + i0 + pi];
    const unsigned char* mp = pk + (unsigned)(i0 + pi) * 512 + jo * 64;
    const float* Bp = expB + (unsigned)head * 4096 + jo * 8;
    const float* Dp = expD + (unsigned)head * 4096 + jo * 8;
    // MFMA role
    int jhalf = wave >> 2, ws = wave & 3;
    int strip = ws & 1, whead = ws >> 1;
    const ushort_t* Vbase = WhT + (unsigned)(hb * 128 + whead * 64 + nn) * 4096
                          + jhalf * 32 + quad * 8;
    bf16x8 onef;
#pragma unroll
    for (int i = 0; i < 8; i++) onef[i] = (short)0x3F80;   // bf16 1.0
    f32x4 acc[4] = {};
    f32x4 accd = {};
    // prologue: tile 0 prefetch
    float4 pBD[2][4]; bf16x8 pV[2][4];
    pBD[0][0] = *(const float4*)(Bp);
    pBD[0][1] = *(const float4*)(Bp + 4);
    pBD[0][2] = *(const float4*)(Dp);
    pBD[0][3] = *(const float4*)(Dp + 4);
#pragma unroll
    for (int nt = 0; nt < 4; nt++)
        pV[0][nt] = *(const bf16x8*)(Vbase + nt * 65536);
    unsigned mcur = *(const unsigned*)(mp);
    for (int t = 0; t < 16; t++) {
        unsigned mnext = (t < 15) ? *(const unsigned*)(mp + (t + 1) * 4) : 0u;
#pragma unroll
        for (int u = 0; u < 4; u++) {
            int k = t * 4 + u;
            int cb = u & 1;           // == k & 1
            int pbuf = cb ^ 1;
            // ---- gen tile k ----
            float4 Bv0 = pBD[cb][0], Bv1 = pBD[cb][1];
            float4 Dv0 = pBD[cb][2], Dv1 = pBD[cb][3];
            unsigned w0, w1, w2, w3, w4, w5, w6, w7;
            {
                float w;
                w = fmaxf(Ai * Bv0.x, Ci * Dv0.x);
                w0 = __builtin_bit_cast(unsigned, w) & 0xFFFF0000u;
                w0 &= (unsigned)__builtin_amdgcn_sbfe(mcur, u * 8 + 0, 1);
                w = fmaxf(Ai * Bv0.y, Ci * Dv0.y);
                w1 = __builtin_bit_cast(unsigned, w) & 0xFFFF0000u;
                w1 &= (unsigned)__builtin_amdgcn_sbfe(mcur, u * 8 + 1, 1);
                w = fmaxf(Ai * Bv0.z, Ci * Dv0.z);
                w2 = __builtin_bit_cast(unsigned, w) & 0xFFFF0000u;
                w2 &= (unsigned)__builtin_amdgcn_sbfe(mcur, u * 8 + 2, 1);
                w = fmaxf(Ai * Bv0.w, Ci * Dv0.w);
                w3 = __builtin_bit_cast(unsigned, w) & 0xFFFF0000u;
                w3 &= (unsigned)__builtin_amdgcn_sbfe(mcur, u * 8 + 3, 1);
                w = fmaxf(Ai * Bv1.x, Ci * Dv1.x);
                w4 = __builtin_bit_cast(unsigned, w) & 0xFFFF0000u;
                w4 &= (unsigned)__builtin_amdgcn_sbfe(mcur, u * 8 + 4, 1);
                w = fmaxf(Ai * Bv1.y, Ci * Dv1.y);
                w5 = __builtin_bit_cast(unsigned, w) & 0xFFFF0000u;
                w5 &= (unsigned)__builtin_amdgcn_sbfe(mcur, u * 8 + 5, 1);
                w = fmaxf(Ai * Bv1.z, Ci * Dv1.z);
                w6 = __builtin_bit_cast(unsigned, w) & 0xFFFF0000u;
                w6 &= (unsigned)__builtin_amdgcn_sbfe(mcur, u * 8 + 6, 1);
                w = fmaxf(Ai * Bv1.w, Ci * Dv1.w);
                w7 = __builtin_bit_cast(unsigned, w) & 0xFFFF0000u;
                w7 &= (unsigned)__builtin_amdgcn_sbfe(mcur, u * 8 + 7, 1);
            }
            uint4 pq;
            pq.x = __builtin_amdgcn_perm(w1, w0, 0x07060302u);
            pq.y = __builtin_amdgcn_perm(w3, w2, 0x07060302u);
            pq.z = __builtin_amdgcn_perm(w5, w4, 0x07060302u);
            pq.w = __builtin_amdgcn_perm(w7, w6, 0x07060302u);
            *(uint4*)&Pb[cb][hh][pi][jo * 8] = pq;
            // ---- prefetch B/D for tile k+1 ----
            if (k < 63) {
                pBD[pbuf][0] = *(const float4*)(Bp + (k + 1) * 64);
                pBD[pbuf][1] = *(const float4*)(Bp + (k + 1) * 64 + 4);
                pBD[pbuf][2] = *(const float4*)(Dp + (k + 1) * 64);
                pBD[pbuf][3] = *(const float4*)(Dp + (k + 1) * 64 + 4);
            }
            // ---- MFMA tile k-1 (reads pV[pbuf]) then prefetch V k+1 into pV[pbuf] ----
            if (k > 0) {
                bf16x8 af = *(const bf16x8*)&Pb[pbuf][whead][strip * 16 + nn][jhalf * 32 + quad * 8];
#pragma unroll
                for (int nt = 0; nt < 4; nt++)
                    acc[nt] = __builtin_amdgcn_mfma_f32_16x16x32_bf16(af, pV[pbuf][nt], acc[nt], 0, 0, 0);
                accd = __builtin_amdgcn_mfma_f32_16x16x32_bf16(af, onef, accd, 0, 0, 0);
            }
            if (k < 63) {
#pragma unroll
                for (int nt = 0; nt < 4; nt++)
                    pV[pbuf][nt] = *(const bf16x8*)(Vbase + nt * 65536 + (k + 1) * 64);
            }
            __syncthreads();   // bottom barrier
        }
        mcur = mnext;
    }
    {   // tail: tile 63 (buffer 1, pV[1])
        bf16x8 af = *(const bf16x8*)&Pb[1][whead][strip * 16 + nn][jhalf * 32 + quad * 8];
#pragma unroll
        for (int nt = 0; nt < 4; nt++)
            acc[nt] = __builtin_amdgcn_mfma_f32_16x16x32_bf16(af, pV[1][nt], acc[nt], 0, 0, 0);
        accd = __builtin_amdgcn_mfma_f32_16x16x32_bf16(af, onef, accd, 0, 0, 0);
    }
    // denominator partials (any col works; use nn==0 lanes)
    if ((lane & 15) == 0) {
#pragma unroll
        for (int rr = 0; rr < 4; rr++)
            denomp[jhalf][whead][strip * 16 + quad * 4 + rr] = accd[rr];
    }
    __syncthreads();   // denomp visible; all Pb[1] tail reads done
    // combine jhalf partials via cmb overlay on Pb slab
    float (*cmb)[64][8] = reinterpret_cast<float (*)[64][8]>(&Pb[0][0][0][0]);
    if (jhalf == 1) {
        *(f32x4*)&cmb[ws][lane][0] = acc[0];
        *(f32x4*)&cmb[ws][lane][4] = acc[1];
    }
    __syncthreads();
    if (jhalf == 0) {
        f32x4 o0 = acc[0] + *(const f32x4*)&cmb[ws][lane][0];
        f32x4 o1 = acc[1] + *(const f32x4*)&cmb[ws][lane][4];
#pragma unroll
        for (int rr = 0; rr < 4; rr++) {
            int il = strip * 16 + quad * 4 + rr;
            float dnm = fmaxf(denomp[0][whead][il] + denomp[1][whead][il], 1e-30f);
            float v0 = o0[rr] / dnm;
            float v1 = o1[rr] / dnm;
            v0 = v0 > 0.f ? v0 : __expf(v0) - 1.f;
            v1 = v1 > 0.f ? v1 : __expf(v1) - 1.f;
            unsigned oi = (unsigned)(i0 + il) * 512 + hb * 128 + whead * 64 + nn;
            out[oi] = v0;
            out[oi + 16] = v1;
        }
    }
    __syncthreads();
    if (jhalf == 1) {
        *(f32x4*)&cmb[ws][lane][0] = acc[2];
        *(f32x4*)&cmb[ws][lane][4] = acc[3];
    }
    __syncthreads();
    if (jhalf == 0) {
        f32x4 o0 = acc[2] + *(const f32x4*)&cmb[ws][lane][0];
        f32x4 o1 = acc[3] + *(const f32x4*)&cmb[ws][lane][4];
#pragma unroll
        for (int rr = 0; rr < 4; rr++) {
            int il = strip * 16 + quad * 4 + rr;
            float dnm = fmaxf(denomp[0][whead][il] + denomp[1][whead][il], 1e-30f);
            float v0 = o0[rr] / dnm;
            float v1 = o1[rr] / dnm;
            v0 = v0 > 0.f ? v0 : __expf(v0) - 1.f;
            v1 = v1 > 0.f ? v1 : __expf(v1) - 1.f;
            unsigned oi = (unsigned)(i0 + il) * 512 + hb * 128 + whead * 64 + 32 + nn;
            out[oi] = v0;
            out[oi + 16] = v1;
        }
    }
}

extern "C" void kernel_launch(void* const* d_in, const int* in_sizes, int n_in,
                              void* d_out, int out_size, void* d_ws, size_t ws_size,
                              hipStream_t stream) {
    const float* h   = (const float*)d_in[0];   // 4096 x 512 fp32
    const int*   adj = (const int*)d_in[1];     // 4096 x 4096 int32
    const float* W   = (const float*)d_in[2];   // 512 x 512 fp32
    const float* a   = (const float*)d_in[3];   // 128 fp32

    char* ws = (char*)d_ws;
    ushort_t* WhT = (ushort_t*)ws;                           // 4 MB
    ushort_t* WT  = (ushort_t*)(ws + (4u << 20));            // 512 KB
    float* expA = (float*)(ws + (4u << 20) + (512u << 10));  // 4 x 128 KB
    float* expC = expA + 8 * 4096;
    float* expB = expC + 8 * 4096;
    float* expD = expB + 8 * 4096;
    unsigned char* pkm = (unsigned char*)(ws + (5u << 20));  // 2 MB bitmask

    pack_adj<<<1024, 256, 0, stream>>>(adj, pkm);
    transpose_w<<<256, 256, 0, stream>>>(W, WT);
    gemm_whT<<<512, 256, 0, stream>>>(WT, h, a, WhT, expA, expC, expB, expD);
    gat_attn<<<512, 512, 0, stream>>>(pkm, WhT, expA, expC, expB, expD,
                                      (float*)d_out);
}

// Round 10
// 178.210 us; speedup vs baseline: 1.5041x; 1.5041x over previous
//
#include <hip/hip_runtime.h>
#include <hip/hip_bf16.h>

// fp32 inputs (confirmed r2). Internal pipeline bf16 MFMA.
// Gen identity: w = exp2(max(e,0.2e)) = max(A_i*B_j, C_i*D_j).
// r10 = mask-packed adj (r9 win) + V through LDS coalesced (r8 law:
//   B-frag loads from global are 64-line scatters -> must stage) +
//   IDENTITY gen->MFMA mapping: each thread generates its own A-fragment
//   in registers (no P LDS, barrier guards V only) + P@ones denominator MFMA.

typedef unsigned short ushort_t;
typedef __attribute__((ext_vector_type(8))) short bf16x8;
typedef __attribute__((ext_vector_type(4))) float f32x4;

#define LOG2E 1.4426950408889634f

__device__ __forceinline__ ushort_t f2bf(float x) {
    unsigned u = __builtin_bit_cast(unsigned, x);
    u += 0x7FFFu + ((u >> 16) & 1u);   // RNE
    return (ushort_t)(u >> 16);
}

// ---------------- kernel 0: pack adj (int32 0/1) -> bitmask (r9 proven) ----------
// byte pk[i*512 + jo*64 + k] holds bits e=0..7 for j = k*64 + jo*8 + e.
__global__ __launch_bounds__(256) void pack_adj(const int* __restrict__ adj,
                                                unsigned char* __restrict__ pk) {
    int wv = threadIdx.x >> 6, lane = threadIdx.x & 63;
    int row = blockIdx.x * 4 + wv;
    const int* ap = adj + (unsigned)row * 4096 + lane;
    unsigned char* pp = pk + (unsigned)row * 512;
    int jo = lane & 7;
#pragma unroll 2
    for (int k4 = 0; k4 < 16; k4++) {
        int v0 = ap[(k4 * 4 + 0) * 64];
        int v1 = ap[(k4 * 4 + 1) * 64];
        int v2 = ap[(k4 * 4 + 2) * 64];
        int v3 = ap[(k4 * 4 + 3) * 64];
        unsigned long long m0 = __ballot(v0 > 0);
        unsigned long long m1 = __ballot(v1 > 0);
        unsigned long long m2 = __ballot(v2 > 0);
        unsigned long long m3 = __ballot(v3 > 0);
        if (lane < 8) {
            int sh = jo * 8;
            unsigned b = ((unsigned)(m0 >> sh) & 0xFFu)
                       | (((unsigned)(m1 >> sh) & 0xFFu) << 8)
                       | (((unsigned)(m2 >> sh) & 0xFFu) << 16)
                       | (((unsigned)(m3 >> sh) & 0xFFu) << 24);
            *(unsigned*)(pp + jo * 64 + k4 * 4) = b;
        }
    }
}

// ---------------- kernel 1: WT[c][k] = W[k][c], 512x512, fp32 -> bf16 ----------------
__global__ __launch_bounds__(256) void transpose_w(const float* __restrict__ W,
                                                   ushort_t* __restrict__ WT) {
    __shared__ ushort_t t[32][33];
    int bx = blockIdx.x & 15, by = blockIdx.x >> 4;
    int tx = threadIdx.x & 31, ty = threadIdx.x >> 5;
#pragma unroll
    for (int i = 0; i < 32; i += 8)
        t[ty + i][tx] = f2bf(W[(by * 32 + ty + i) * 512 + bx * 32 + tx]);
    __syncthreads();
#pragma unroll
    for (int i = 0; i < 32; i += 8)
        WT[(bx * 32 + ty + i) * 512 + by * 32 + tx] = t[tx][ty + i];
}

// -------- kernel 2: WhT = WT @ h^T, pipelined (r8 proven) + exp epilogue --------
__global__ __launch_bounds__(256, 4) void gemm_whT(const ushort_t* __restrict__ WT,
                                                   const float* __restrict__ h,
                                                   const float* __restrict__ a,
                                                   ushort_t* __restrict__ WhT,
                                                   float* __restrict__ expA,
                                                   float* __restrict__ expC,
                                                   float* __restrict__ expB,
                                                   float* __restrict__ expD) {
    __shared__ __align__(16) ushort_t Al[2][64][72];
    __shared__ __align__(16) ushort_t Bl[2][64][72];
    __shared__ float asrc[64], adst[64];
    __shared__ float sred[2][4][64];
    int tid = threadIdx.x;
    int wave = tid >> 6, lane = tid & 63, quad = lane >> 4, nn = lane & 15;
    int mb = blockIdx.x & 7, nb = blockIdx.x >> 3;
    if (tid < 64) {
        asrc[tid] = a[tid] * LOG2E;
        adst[tid] = a[64 + tid] * LOG2E;
    }
    int r = tid >> 2, s0 = tid & 3;
    const ushort_t* Ag = WT + (unsigned)((mb * 64 + r) * 512 + s0 * 8);
    const float* Bg = h + (unsigned)((nb * 64 + r) * 512 + s0 * 8);
    bf16x8 pA0 = *(const bf16x8*)(Ag);
    bf16x8 pA1 = *(const bf16x8*)(Ag + 32);
    float4 pb0 = *(const float4*)(Bg);
    float4 pb1 = *(const float4*)(Bg + 4);
    float4 pb2 = *(const float4*)(Bg + 32);
    float4 pb3 = *(const float4*)(Bg + 36);
    f32x4 acc[4] = {};
#pragma unroll 2
    for (int t = 0; t < 8; t++) {
        int cb = t & 1;
        *(bf16x8*)&Al[cb][r][s0 * 8] = pA0;
        *(bf16x8*)&Al[cb][r][s0 * 8 + 32] = pA1;
        bf16x8 bv;
        bv[0] = (short)f2bf(pb0.x); bv[1] = (short)f2bf(pb0.y);
        bv[2] = (short)f2bf(pb0.z); bv[3] = (short)f2bf(pb0.w);
        bv[4] = (short)f2bf(pb1.x); bv[5] = (short)f2bf(pb1.y);
        bv[6] = (short)f2bf(pb1.z); bv[7] = (short)f2bf(pb1.w);
        *(bf16x8*)&Bl[cb][r][s0 * 8] = bv;
        bv[0] = (short)f2bf(pb2.x); bv[1] = (short)f2bf(pb2.y);
        bv[2] = (short)f2bf(pb2.z); bv[3] = (short)f2bf(pb2.w);
        bv[4] = (short)f2bf(pb3.x); bv[5] = (short)f2bf(pb3.y);
        bv[6] = (short)f2bf(pb3.z); bv[7] = (short)f2bf(pb3.w);
        *(bf16x8*)&Bl[cb][r][s0 * 8 + 32] = bv;
        if (t < 7) {
            int ko = (t + 1) * 64;
            pA0 = *(const bf16x8*)(Ag + ko);
            pA1 = *(const bf16x8*)(Ag + ko + 32);
            pb0 = *(const float4*)(Bg + ko);
            pb1 = *(const float4*)(Bg + ko + 4);
            pb2 = *(const float4*)(Bg + ko + 32);
            pb3 = *(const float4*)(Bg + ko + 36);
        }
        if (t > 0) {
            int pb = cb ^ 1;
            bf16x8 af0 = *(const bf16x8*)&Al[pb][wave * 16 + nn][quad * 8];
            bf16x8 af1 = *(const bf16x8*)&Al[pb][wave * 16 + nn][32 + quad * 8];
#pragma unroll
            for (int nt = 0; nt < 4; nt++) {
                bf16x8 b0 = *(const bf16x8*)&Bl[pb][nt * 16 + nn][quad * 8];
                bf16x8 b1 = *(const bf16x8*)&Bl[pb][nt * 16 + nn][32 + quad * 8];
                acc[nt] = __builtin_amdgcn_mfma_f32_16x16x32_bf16(af0, b0, acc[nt], 0, 0, 0);
                acc[nt] = __builtin_amdgcn_mfma_f32_16x16x32_bf16(af1, b1, acc[nt], 0, 0, 0);
            }
        }
        __syncthreads();
    }
    {
        bf16x8 af0 = *(const bf16x8*)&Al[1][wave * 16 + nn][quad * 8];
        bf16x8 af1 = *(const bf16x8*)&Al[1][wave * 16 + nn][32 + quad * 8];
#pragma unroll
        for (int nt = 0; nt < 4; nt++) {
            bf16x8 b0 = *(const bf16x8*)&Bl[1][nt * 16 + nn][quad * 8];
            bf16x8 b1 = *(const bf16x8*)&Bl[1][nt * 16 + nn][32 + quad * 8];
            acc[nt] = __builtin_amdgcn_mfma_f32_16x16x32_bf16(af0, b0, acc[nt], 0, 0, 0);
            acc[nt] = __builtin_amdgcn_mfma_f32_16x16x32_bf16(af1, b1, acc[nt], 0, 0, 0);
        }
    }
    int row0 = mb * 64 + wave * 16 + quad * 4;
    int col0 = nb * 64 + nn;
    int f0i = wave * 16 + quad * 4;
#pragma unroll
    for (int nt = 0; nt < 4; nt++) {
        float s = 0.f, d = 0.f;
#pragma unroll
        for (int rr = 0; rr < 4; rr++) {
            float v = acc[nt][rr];
            WhT[(unsigned)((row0 + rr) * 4096 + col0 + nt * 16)] = f2bf(v);
            s += v * asrc[f0i + rr];
            d += v * adst[f0i + rr];
        }
        s += __shfl_xor(s, 16); s += __shfl_xor(s, 32);
        d += __shfl_xor(d, 16); d += __shfl_xor(d, 32);
        if (quad == 0) { sred[0][wave][nt * 16 + nn] = s; sred[1][wave][nt * 16 + nn] = d; }
    }
    __syncthreads();
    if (tid < 64) {
        float s = sred[0][0][tid] + sred[0][1][tid] + sred[0][2][tid] + sred[0][3][tid];
        unsigned idx = mb * 4096 + nb * 64 + tid;
        expA[idx] = __builtin_amdgcn_exp2f(s);
        expC[idx] = __builtin_amdgcn_exp2f(0.2f * s);
    } else if (tid < 128) {
        int c = tid - 64;
        float d = sred[1][0][c] + sred[1][1][c] + sred[1][2][c] + sred[1][3][c];
        unsigned idx = mb * 4096 + nb * 64 + c;
        expB[idx] = __builtin_amdgcn_exp2f(d);
        expD[idx] = __builtin_amdgcn_exp2f(0.2f * d);
    }
}

// -------- kernel 3: fused attention, identity gen->MFMA mapping --------
// 512 blocks x 512 thr (512,4). i-tile 32 x 2 heads; j-tile 64; V dbuf LDS only.
// Each thread generates its own A-fragment: hh=whead, pi=strip*16+nn,
// jo=jhalf*4+quad (bijection over 512 threads). One barrier/iter between
// V-store and MFMA. Denominator via P@ones MFMA.
__global__ __launch_bounds__(512, 4) void gat_attn(const unsigned char* __restrict__ pk,
                                                   const ushort_t* __restrict__ WhT,
                                                   const float* __restrict__ expA,
                                                   const float* __restrict__ expC,
                                                   const float* __restrict__ expB,
                                                   const float* __restrict__ expD,
                                                   float* __restrict__ out) {
    __shared__ __align__(16) ushort_t Vb[2][128][72];   // 36864 B (cmb overlays Vb[0])
    __shared__ float denomp[2][2][32];
    int tid = threadIdx.x;
    int wave = tid >> 6, lane = tid & 63, quad = lane >> 4, nn = lane & 15;
    int hb = blockIdx.x >> 7, ib = blockIdx.x & 127;   // adj row-band on one XCD
    int i0 = ib * 32;
    // identity mapping: this thread's gen == its MFMA A-fragment
    int jhalf = wave >> 2, ws = wave & 3;
    int whead = ws >> 1, strip = ws & 1;
    int pi = strip * 16 + nn, jo = jhalf * 4 + quad;
    int head = hb * 2 + whead;
    float Ai = expA[head * 4096 + i0 + pi];
    float Ci = expC[head * 4096 + i0 + pi];
    const unsigned char* mp = pk + (unsigned)(i0 + pi) * 512 + jo * 64;
    const float* Bp = expB + (unsigned)head * 4096 + jo * 8;
    const float* Dp = expD + (unsigned)head * 4096 + jo * 8;
    // V staging role (coalesced): rows vr, vr+64; 16B col-seg vcs
    int vr = tid >> 3, vcs = tid & 7;
    const ushort_t* Vg0 = WhT + (unsigned)(hb * 128 + vr) * 4096 + vcs * 8;
    const ushort_t* Vg1 = Vg0 + 64u * 4096u;
    bf16x8 onef;
#pragma unroll
    for (int i = 0; i < 8; i++) onef[i] = (short)0x3F80;   // bf16 1.0
    f32x4 acc[4] = {};
    f32x4 accd = {};
    // prologue: prefetch tile 0
    bf16x8 pv0 = *(const bf16x8*)(Vg0);
    bf16x8 pv1 = *(const bf16x8*)(Vg1);
    float4 pBD[2][4];
    pBD[0][0] = *(const float4*)(Bp);
    pBD[0][1] = *(const float4*)(Bp + 4);
    pBD[0][2] = *(const float4*)(Dp);
    pBD[0][3] = *(const float4*)(Dp + 4);
    unsigned mcur = *(const unsigned*)(mp);
    for (int t = 0; t < 16; t++) {
        unsigned mnext = (t < 15) ? *(const unsigned*)(mp + (t + 1) * 4) : 0u;
#pragma unroll
        for (int u = 0; u < 4; u++) {
            int k = t * 4 + u;
            int cb = k & 1, pbuf = cb ^ 1;
            // ---- store V tile k (from prefetch regs) ----
            *(bf16x8*)&Vb[cb][vr][vcs * 8] = pv0;
            *(bf16x8*)&Vb[cb][64 + vr][vcs * 8] = pv1;
            // ---- issue prefetch tile k+1 (V, B/D) ----
            if (k < 63) {
                pv0 = *(const bf16x8*)(Vg0 + (k + 1) * 64);
                pv1 = *(const bf16x8*)(Vg1 + (k + 1) * 64);
                pBD[pbuf][0] = *(const float4*)(Bp + (k + 1) * 64);
                pBD[pbuf][1] = *(const float4*)(Bp + (k + 1) * 64 + 4);
                pBD[pbuf][2] = *(const float4*)(Dp + (k + 1) * 64);
                pBD[pbuf][3] = *(const float4*)(Dp + (k + 1) * 64 + 4);
            }
            // ---- gen tile k: own A-fragment in registers ----
            float4 Bv0 = pBD[cb][0], Bv1 = pBD[cb][1];
            float4 Dv0 = pBD[cb][2], Dv1 = pBD[cb][3];
            unsigned w0, w1, w2, w3, w4, w5, w6, w7;
            {
                float w;
                w = fmaxf(Ai * Bv0.x, Ci * Dv0.x);
                w0 = __builtin_bit_cast(unsigned, w) & 0xFFFF0000u;
                w0 &= (unsigned)__builtin_amdgcn_sbfe(mcur, u * 8 + 0, 1);
                w = fmaxf(Ai * Bv0.y, Ci * Dv0.y);
                w1 = __builtin_bit_cast(unsigned, w) & 0xFFFF0000u;
                w1 &= (unsigned)__builtin_amdgcn_sbfe(mcur, u * 8 + 1, 1);
                w = fmaxf(Ai * Bv0.z, Ci * Dv0.z);
                w2 = __builtin_bit_cast(unsigned, w) & 0xFFFF0000u;
                w2 &= (unsigned)__builtin_amdgcn_sbfe(mcur, u * 8 + 2, 1);
                w = fmaxf(Ai * Bv0.w, Ci * Dv0.w);
                w3 = __builtin_bit_cast(unsigned, w) & 0xFFFF0000u;
                w3 &= (unsigned)__builtin_amdgcn_sbfe(mcur, u * 8 + 3, 1);
                w = fmaxf(Ai * Bv1.x, Ci * Dv1.x);
                w4 = __builtin_bit_cast(unsigned, w) & 0xFFFF0000u;
                w4 &= (unsigned)__builtin_amdgcn_sbfe(mcur, u * 8 + 4, 1);
                w = fmaxf(Ai * Bv1.y, Ci * Dv1.y);
                w5 = __builtin_bit_cast(unsigned, w) & 0xFFFF0000u;
                w5 &= (unsigned)__builtin_amdgcn_sbfe(mcur, u * 8 + 5, 1);
                w = fmaxf(Ai * Bv1.z, Ci * Dv1.z);
                w6 = __builtin_bit_cast(unsigned, w) & 0xFFFF0000u;
                w6 &= (unsigned)__builtin_amdgcn_sbfe(mcur, u * 8 + 6, 1);
                w = fmaxf(Ai * Bv1.w, Ci * Dv1.w);
                w7 = __builtin_bit_cast(unsigned, w) & 0xFFFF0000u;
                w7 &= (unsigned)__builtin_amdgcn_sbfe(mcur, u * 8 + 7, 1);
            }
            uint4 pq;
            pq.x = __builtin_amdgcn_perm(w1, w0, 0x07060302u);
            pq.y = __builtin_amdgcn_perm(w3, w2, 0x07060302u);
            pq.z = __builtin_amdgcn_perm(w5, w4, 0x07060302u);
            pq.w = __builtin_amdgcn_perm(w7, w6, 0x07060302u);
            bf16x8 af = __builtin_bit_cast(bf16x8, pq);
            __syncthreads();   // V tile k visible; prev readers done
            // ---- MFMA tile k: af (regs) x Vb[cb] ----
#pragma unroll
            for (int nt = 0; nt < 4; nt++) {
                bf16x8 bv = *(const bf16x8*)&Vb[cb][whead * 64 + nt * 16 + nn][jhalf * 32 + quad * 8];
                acc[nt] = __builtin_amdgcn_mfma_f32_16x16x32_bf16(af, bv, acc[nt], 0, 0, 0);
            }
            accd = __builtin_amdgcn_mfma_f32_16x16x32_bf16(af, onef, accd, 0, 0, 0);
        }
        mcur = mnext;
    }
    // denominator partials: C-layout row = quad*4+rr (any col; use nn==0 lanes)
    if (nn == 0) {
#pragma unroll
        for (int rr = 0; rr < 4; rr++)
            denomp[jhalf][whead][strip * 16 + quad * 4 + rr] = accd[rr];
    }
    __syncthreads();   // denomp visible; all Vb reads of k=63 done
    // combine jhalf partials via cmb overlay on Vb[0] slab
    float (*cmb)[64][8] = reinterpret_cast<float (*)[64][8]>(&Vb[0][0][0]);
    if (jhalf == 1) {
        *(f32x4*)&cmb[ws][lane][0] = acc[0];
        *(f32x4*)&cmb[ws][lane][4] = acc[1];
    }
    __syncthreads();
    if (jhalf == 0) {
        f32x4 o0 = acc[0] + *(const f32x4*)&cmb[ws][lane][0];
        f32x4 o1 = acc[1] + *(const f32x4*)&cmb[ws][lane][4];
#pragma unroll
        for (int rr = 0; rr < 4; rr++) {
            int il = strip * 16 + quad * 4 + rr;
            float dnm = fmaxf(denomp[0][whead][il] + denomp[1][whead][il], 1e-30f);
            float v0 = o0[rr] / dnm;
            float v1 = o1[rr] / dnm;
            v0 = v0 > 0.f ? v0 : __expf(v0) - 1.f;
            v1 = v1 > 0.f ? v1 : __expf(v1) - 1.f;
            unsigned oi = (unsigned)(i0 + il) * 512 + hb * 128 + whead * 64 + nn;
            out[oi] = v0;
            out[oi + 16] = v1;
        }
    }
    __syncthreads();
    if (jhalf == 1) {
        *(f32x4*)&cmb[ws][lane][0] = acc[2];
        *(f32x4*)&cmb[ws][lane][4] = acc[3];
    }
    __syncthreads();
    if (jhalf == 0) {
        f32x4 o0 = acc[2] + *(const f32x4*)&cmb[ws][lane][0];
        f32x4 o1 = acc[3] + *(const f32x4*)&cmb[ws][lane][4];
#pragma unroll
        for (int rr = 0; rr < 4; rr++) {
            int il = strip * 16 + quad * 4 + rr;
            float dnm = fmaxf(denomp[0][whead][il] + denomp[1][whead][il], 1e-30f);
            float v0 = o0[rr] / dnm;
            float v1 = o1[rr] / dnm;
            v0 = v0 > 0.f ? v0 : __expf(v0) - 1.f;
            v1 = v1 > 0.f ? v1 : __expf(v1) - 1.f;
            unsigned oi = (unsigned)(i0 + il) * 512 + hb * 128 + whead * 64 + 32 + nn;
            out[oi] = v0;
            out[oi + 16] = v1;
        }
    }
}

extern "C" void kernel_launch(void* const* d_in, const int* in_sizes, int n_in,
                              void* d_out, int out_size, void* d_ws, size_t ws_size,
                              hipStream_t stream) {
    const float* h   = (const float*)d_in[0];   // 4096 x 512 fp32
    const int*   adj = (const int*)d_in[1];     // 4096 x 4096 int32
    const float* W   = (const float*)d_in[2];   // 512 x 512 fp32
    const float* a   = (const float*)d_in[3];   // 128 fp32

    char* ws = (char*)d_ws;
    ushort_t* WhT = (ushort_t*)ws;                           // 4 MB
    ushort_t* WT  = (ushort_t*)(ws + (4u << 20));            // 512 KB
    float* expA = (float*)(ws + (4u << 20) + (512u << 10));  // 4 x 128 KB
    float* expC = expA + 8 * 4096;
    float* expB = expC + 8 * 4096;
    float* expD = expB + 8 * 4096;
    unsigned char* pkm = (unsigned char*)(ws + (5u << 20));  // 2 MB bitmask

    pack_adj<<<1024, 256, 0, stream>>>(adj, pkm);
    transpose_w<<<256, 256, 0, stream>>>(W, WT);
    gemm_whT<<<512, 256, 0, stream>>>(WT, h, a, WhT, expA, expC, expB, expD);
    gat_attn<<<512, 512, 0, stream>>>(pkm, WhT, expA, expC, expB, expD,
                                      (float*)d_out);
}

// Round 11
// 175.565 us; speedup vs baseline: 1.5268x; 1.0151x over previous
//
#include <hip/hip_runtime.h>
#include <hip/hip_bf16.h>

// fp32 inputs (confirmed r2). Internal pipeline bf16 MFMA.
// Gen identity: w = exp2(max(e,0.2e)) = max(A_i*B_j, C_i*D_j).
// r11 = r10 with ONE change: prefetch loads issued AFTER __syncthreads
//   (pinned by sched_barrier(0)). The compiler's `s_waitcnt vmcnt(0)` before
//   s_barrier then drains nothing recent -> barrier drain ~0 (was ~50% idle).

typedef unsigned short ushort_t;
typedef __attribute__((ext_vector_type(8))) short bf16x8;
typedef __attribute__((ext_vector_type(4))) float f32x4;

#define LOG2E 1.4426950408889634f

__device__ __forceinline__ ushort_t f2bf(float x) {
    unsigned u = __builtin_bit_cast(unsigned, x);
    u += 0x7FFFu + ((u >> 16) & 1u);   // RNE
    return (ushort_t)(u >> 16);
}

// ---------------- kernel 0: pack adj (int32 0/1) -> bitmask (r9 proven) ----------
__global__ __launch_bounds__(256) void pack_adj(const int* __restrict__ adj,
                                                unsigned char* __restrict__ pk) {
    int wv = threadIdx.x >> 6, lane = threadIdx.x & 63;
    int row = blockIdx.x * 4 + wv;
    const int* ap = adj + (unsigned)row * 4096 + lane;
    unsigned char* pp = pk + (unsigned)row * 512;
    int jo = lane & 7;
#pragma unroll 2
    for (int k4 = 0; k4 < 16; k4++) {
        int v0 = ap[(k4 * 4 + 0) * 64];
        int v1 = ap[(k4 * 4 + 1) * 64];
        int v2 = ap[(k4 * 4 + 2) * 64];
        int v3 = ap[(k4 * 4 + 3) * 64];
        unsigned long long m0 = __ballot(v0 > 0);
        unsigned long long m1 = __ballot(v1 > 0);
        unsigned long long m2 = __ballot(v2 > 0);
        unsigned long long m3 = __ballot(v3 > 0);
        if (lane < 8) {
            int sh = jo * 8;
            unsigned b = ((unsigned)(m0 >> sh) & 0xFFu)
                       | (((unsigned)(m1 >> sh) & 0xFFu) << 8)
                       | (((unsigned)(m2 >> sh) & 0xFFu) << 16)
                       | (((unsigned)(m3 >> sh) & 0xFFu) << 24);
            *(unsigned*)(pp + jo * 64 + k4 * 4) = b;
        }
    }
}

// ---------------- kernel 1: WT[c][k] = W[k][c], 512x512, fp32 -> bf16 ----------------
__global__ __launch_bounds__(256) void transpose_w(const float* __restrict__ W,
                                                   ushort_t* __restrict__ WT) {
    __shared__ ushort_t t[32][33];
    int bx = blockIdx.x & 15, by = blockIdx.x >> 4;
    int tx = threadIdx.x & 31, ty = threadIdx.x >> 5;
#pragma unroll
    for (int i = 0; i < 32; i += 8)
        t[ty + i][tx] = f2bf(W[(by * 32 + ty + i) * 512 + bx * 32 + tx]);
    __syncthreads();
#pragma unroll
    for (int i = 0; i < 32; i += 8)
        WT[(bx * 32 + ty + i) * 512 + by * 32 + tx] = t[tx][ty + i];
}

// -------- kernel 2: WhT = WT @ h^T, pipelined (r8 proven) + exp epilogue --------
__global__ __launch_bounds__(256, 4) void gemm_whT(const ushort_t* __restrict__ WT,
                                                   const float* __restrict__ h,
                                                   const float* __restrict__ a,
                                                   ushort_t* __restrict__ WhT,
                                                   float* __restrict__ expA,
                                                   float* __restrict__ expC,
                                                   float* __restrict__ expB,
                                                   float* __restrict__ expD) {
    __shared__ __align__(16) ushort_t Al[2][64][72];
    __shared__ __align__(16) ushort_t Bl[2][64][72];
    __shared__ float asrc[64], adst[64];
    __shared__ float sred[2][4][64];
    int tid = threadIdx.x;
    int wave = tid >> 6, lane = tid & 63, quad = lane >> 4, nn = lane & 15;
    int mb = blockIdx.x & 7, nb = blockIdx.x >> 3;
    if (tid < 64) {
        asrc[tid] = a[tid] * LOG2E;
        adst[tid] = a[64 + tid] * LOG2E;
    }
    int r = tid >> 2, s0 = tid & 3;
    const ushort_t* Ag = WT + (unsigned)((mb * 64 + r) * 512 + s0 * 8);
    const float* Bg = h + (unsigned)((nb * 64 + r) * 512 + s0 * 8);
    bf16x8 pA0 = *(const bf16x8*)(Ag);
    bf16x8 pA1 = *(const bf16x8*)(Ag + 32);
    float4 pb0 = *(const float4*)(Bg);
    float4 pb1 = *(const float4*)(Bg + 4);
    float4 pb2 = *(const float4*)(Bg + 32);
    float4 pb3 = *(const float4*)(Bg + 36);
    f32x4 acc[4] = {};
#pragma unroll 2
    for (int t = 0; t < 8; t++) {
        int cb = t & 1;
        *(bf16x8*)&Al[cb][r][s0 * 8] = pA0;
        *(bf16x8*)&Al[cb][r][s0 * 8 + 32] = pA1;
        bf16x8 bv;
        bv[0] = (short)f2bf(pb0.x); bv[1] = (short)f2bf(pb0.y);
        bv[2] = (short)f2bf(pb0.z); bv[3] = (short)f2bf(pb0.w);
        bv[4] = (short)f2bf(pb1.x); bv[5] = (short)f2bf(pb1.y);
        bv[6] = (short)f2bf(pb1.z); bv[7] = (short)f2bf(pb1.w);
        *(bf16x8*)&Bl[cb][r][s0 * 8] = bv;
        bv[0] = (short)f2bf(pb2.x); bv[1] = (short)f2bf(pb2.y);
        bv[2] = (short)f2bf(pb2.z); bv[3] = (short)f2bf(pb2.w);
        bv[4] = (short)f2bf(pb3.x); bv[5] = (short)f2bf(pb3.y);
        bv[6] = (short)f2bf(pb3.z); bv[7] = (short)f2bf(pb3.w);
        *(bf16x8*)&Bl[cb][r][s0 * 8 + 32] = bv;
        if (t < 7) {
            int ko = (t + 1) * 64;
            pA0 = *(const bf16x8*)(Ag + ko);
            pA1 = *(const bf16x8*)(Ag + ko + 32);
            pb0 = *(const float4*)(Bg + ko);
            pb1 = *(const float4*)(Bg + ko + 4);
            pb2 = *(const float4*)(Bg + ko + 32);
            pb3 = *(const float4*)(Bg + ko + 36);
        }
        if (t > 0) {
            int pb = cb ^ 1;
            bf16x8 af0 = *(const bf16x8*)&Al[pb][wave * 16 + nn][quad * 8];
            bf16x8 af1 = *(const bf16x8*)&Al[pb][wave * 16 + nn][32 + quad * 8];
#pragma unroll
            for (int nt = 0; nt < 4; nt++) {
                bf16x8 b0 = *(const bf16x8*)&Bl[pb][nt * 16 + nn][quad * 8];
                bf16x8 b1 = *(const bf16x8*)&Bl[pb][nt * 16 + nn][32 + quad * 8];
                acc[nt] = __builtin_amdgcn_mfma_f32_16x16x32_bf16(af0, b0, acc[nt], 0, 0, 0);
                acc[nt] = __builtin_amdgcn_mfma_f32_16x16x32_bf16(af1, b1, acc[nt], 0, 0, 0);
            }
        }
        __syncthreads();
    }
    {
        bf16x8 af0 = *(const bf16x8*)&Al[1][wave * 16 + nn][quad * 8];
        bf16x8 af1 = *(const bf16x8*)&Al[1][wave * 16 + nn][32 + quad * 8];
#pragma unroll
        for (int nt = 0; nt < 4; nt++) {
            bf16x8 b0 = *(const bf16x8*)&Bl[1][nt * 16 + nn][quad * 8];
            bf16x8 b1 = *(const bf16x8*)&Bl[1][nt * 16 + nn][32 + quad * 8];
            acc[nt] = __builtin_amdgcn_mfma_f32_16x16x32_bf16(af0, b0, acc[nt], 0, 0, 0);
            acc[nt] = __builtin_amdgcn_mfma_f32_16x16x32_bf16(af1, b1, acc[nt], 0, 0, 0);
        }
    }
    int row0 = mb * 64 + wave * 16 + quad * 4;
    int col0 = nb * 64 + nn;
    int f0i = wave * 16 + quad * 4;
#pragma unroll
    for (int nt = 0; nt < 4; nt++) {
        float s = 0.f, d = 0.f;
#pragma unroll
        for (int rr = 0; rr < 4; rr++) {
            float v = acc[nt][rr];
            WhT[(unsigned)((row0 + rr) * 4096 + col0 + nt * 16)] = f2bf(v);
            s += v * asrc[f0i + rr];
            d += v * adst[f0i + rr];
        }
        s += __shfl_xor(s, 16); s += __shfl_xor(s, 32);
        d += __shfl_xor(d, 16); d += __shfl_xor(d, 32);
        if (quad == 0) { sred[0][wave][nt * 16 + nn] = s; sred[1][wave][nt * 16 + nn] = d; }
    }
    __syncthreads();
    if (tid < 64) {
        float s = sred[0][0][tid] + sred[0][1][tid] + sred[0][2][tid] + sred[0][3][tid];
        unsigned idx = mb * 4096 + nb * 64 + tid;
        expA[idx] = __builtin_amdgcn_exp2f(s);
        expC[idx] = __builtin_amdgcn_exp2f(0.2f * s);
    } else if (tid < 128) {
        int c = tid - 64;
        float d = sred[1][0][c] + sred[1][1][c] + sred[1][2][c] + sred[1][3][c];
        unsigned idx = mb * 4096 + nb * 64 + c;
        expB[idx] = __builtin_amdgcn_exp2f(d);
        expD[idx] = __builtin_amdgcn_exp2f(0.2f * d);
    }
}

// -------- kernel 3: fused attention, identity mapping, post-barrier prefetch --------
// 512 blocks x 512 thr (512,4). i-tile 32 x 2 heads; j-tile 64; V dbuf LDS.
// Per iter: store V(k); gen(k); BARRIER; [sched fence] prefetch(k+1); MFMA(k).
// At each barrier no recent loads are outstanding -> drain ~free.
__global__ __launch_bounds__(512, 4) void gat_attn(const unsigned char* __restrict__ pk,
                                                   const ushort_t* __restrict__ WhT,
                                                   const float* __restrict__ expA,
                                                   const float* __restrict__ expC,
                                                   const float* __restrict__ expB,
                                                   const float* __restrict__ expD,
                                                   float* __restrict__ out) {
    __shared__ __align__(16) ushort_t Vb[2][128][72];   // 36864 B (cmb overlays Vb[0])
    __shared__ float denomp[2][2][32];
    int tid = threadIdx.x;
    int wave = tid >> 6, lane = tid & 63, quad = lane >> 4, nn = lane & 15;
    int hb = blockIdx.x >> 7, ib = blockIdx.x & 127;   // adj row-band on one XCD
    int i0 = ib * 32;
    // identity mapping: this thread's gen == its MFMA A-fragment
    int jhalf = wave >> 2, ws = wave & 3;
    int whead = ws >> 1, strip = ws & 1;
    int pi = strip * 16 + nn, jo = jhalf * 4 + quad;
    int head = hb * 2 + whead;
    float Ai = expA[head * 4096 + i0 + pi];
    float Ci = expC[head * 4096 + i0 + pi];
    const unsigned char* mp = pk + (unsigned)(i0 + pi) * 512 + jo * 64;
    const float* Bp = expB + (unsigned)head * 4096 + jo * 8;
    const float* Dp = expD + (unsigned)head * 4096 + jo * 8;
    // V staging role (coalesced): rows vr, vr+64; 16B col-seg vcs
    int vr = tid >> 3, vcs = tid & 7;
    const ushort_t* Vg0 = WhT + (unsigned)(hb * 128 + vr) * 4096 + vcs * 8;
    const ushort_t* Vg1 = Vg0 + 64u * 4096u;
    bf16x8 onef;
#pragma unroll
    for (int i = 0; i < 8; i++) onef[i] = (short)0x3F80;   // bf16 1.0
    f32x4 acc[4] = {};
    f32x4 accd = {};
    // prologue: prefetch tile 0
    bf16x8 pv0 = *(const bf16x8*)(Vg0);
    bf16x8 pv1 = *(const bf16x8*)(Vg1);
    float4 pBD[2][4];
    pBD[0][0] = *(const float4*)(Bp);
    pBD[0][1] = *(const float4*)(Bp + 4);
    pBD[0][2] = *(const float4*)(Dp);
    pBD[0][3] = *(const float4*)(Dp + 4);
    unsigned mcur = *(const unsigned*)(mp);
    unsigned mnext = 0;
    for (int t = 0; t < 16; t++) {
#pragma unroll
        for (int u = 0; u < 4; u++) {
            int k = t * 4 + u;
            int cb = k & 1, pbuf = cb ^ 1;
            // ---- store V tile k (from prefetch regs) ----
            *(bf16x8*)&Vb[cb][vr][vcs * 8] = pv0;
            *(bf16x8*)&Vb[cb][64 + vr][vcs * 8] = pv1;
            // ---- gen tile k: own A-fragment in registers ----
            float4 Bv0 = pBD[cb][0], Bv1 = pBD[cb][1];
            float4 Dv0 = pBD[cb][2], Dv1 = pBD[cb][3];
            unsigned w0, w1, w2, w3, w4, w5, w6, w7;
            {
                float w;
                w = fmaxf(Ai * Bv0.x, Ci * Dv0.x);
                w0 = __builtin_bit_cast(unsigned, w) & 0xFFFF0000u;
                w0 &= (unsigned)__builtin_amdgcn_sbfe(mcur, u * 8 + 0, 1);
                w = fmaxf(Ai * Bv0.y, Ci * Dv0.y);
                w1 = __builtin_bit_cast(unsigned, w) & 0xFFFF0000u;
                w1 &= (unsigned)__builtin_amdgcn_sbfe(mcur, u * 8 + 1, 1);
                w = fmaxf(Ai * Bv0.z, Ci * Dv0.z);
                w2 = __builtin_bit_cast(unsigned, w) & 0xFFFF0000u;
                w2 &= (unsigned)__builtin_amdgcn_sbfe(mcur, u * 8 + 2, 1);
                w = fmaxf(Ai * Bv0.w, Ci * Dv0.w);
                w3 = __builtin_bit_cast(unsigned, w) & 0xFFFF0000u;
                w3 &= (unsigned)__builtin_amdgcn_sbfe(mcur, u * 8 + 3, 1);
                w = fmaxf(Ai * Bv1.x, Ci * Dv1.x);
                w4 = __builtin_bit_cast(unsigned, w) & 0xFFFF0000u;
                w4 &= (unsigned)__builtin_amdgcn_sbfe(mcur, u * 8 + 4, 1);
                w = fmaxf(Ai * Bv1.y, Ci * Dv1.y);
                w5 = __builtin_bit_cast(unsigned, w) & 0xFFFF0000u;
                w5 &= (unsigned)__builtin_amdgcn_sbfe(mcur, u * 8 + 5, 1);
                w = fmaxf(Ai * Bv1.z, Ci * Dv1.z);
                w6 = __builtin_bit_cast(unsigned, w) & 0xFFFF0000u;
                w6 &= (unsigned)__builtin_amdgcn_sbfe(mcur, u * 8 + 6, 1);
                w = fmaxf(Ai * Bv1.w, Ci * Dv1.w);
                w7 = __builtin_bit_cast(unsigned, w) & 0xFFFF0000u;
                w7 &= (unsigned)__builtin_amdgcn_sbfe(mcur, u * 8 + 7, 1);
            }
            uint4 pq;
            pq.x = __builtin_amdgcn_perm(w1, w0, 0x07060302u);
            pq.y = __builtin_amdgcn_perm(w3, w2, 0x07060302u);
            pq.z = __builtin_amdgcn_perm(w5, w4, 0x07060302u);
            pq.w = __builtin_amdgcn_perm(w7, w6, 0x07060302u);
            bf16x8 af = __builtin_bit_cast(bf16x8, pq);
            if (u == 3) mcur = mnext;
            __syncthreads();                       // drains only old loads (~free)
            __builtin_amdgcn_sched_barrier(0);     // pin: loads below stay below
            // ---- prefetch tile k+1 (issued post-barrier: drained next iter,
            //      by which time they are ~1 full iteration old) ----
            if (k < 63) {
                pv0 = *(const bf16x8*)(Vg0 + (k + 1) * 64);
                pv1 = *(const bf16x8*)(Vg1 + (k + 1) * 64);
                pBD[pbuf][0] = *(const float4*)(Bp + (k + 1) * 64);
                pBD[pbuf][1] = *(const float4*)(Bp + (k + 1) * 64 + 4);
                pBD[pbuf][2] = *(const float4*)(Dp + (k + 1) * 64);
                pBD[pbuf][3] = *(const float4*)(Dp + (k + 1) * 64 + 4);
            }
            if (u == 0 && t < 15) mnext = *(const unsigned*)(mp + (t + 1) * 4);
            // ---- MFMA tile k: af (regs) x Vb[cb] ----
#pragma unroll
            for (int nt = 0; nt < 4; nt++) {
                bf16x8 bv = *(const bf16x8*)&Vb[cb][whead * 64 + nt * 16 + nn][jhalf * 32 + quad * 8];
                acc[nt] = __builtin_amdgcn_mfma_f32_16x16x32_bf16(af, bv, acc[nt], 0, 0, 0);
            }
            accd = __builtin_amdgcn_mfma_f32_16x16x32_bf16(af, onef, accd, 0, 0, 0);
        }
    }
    // denominator partials: C-layout row = quad*4+rr (any col; use nn==0 lanes)
    if (nn == 0) {
#pragma unroll
        for (int rr = 0; rr < 4; rr++)
            denomp[jhalf][whead][strip * 16 + quad * 4 + rr] = accd[rr];
    }
    __syncthreads();   // denomp visible; all Vb reads of k=63 done
    // combine jhalf partials via cmb overlay on Vb[0] slab
    float (*cmb)[64][8] = reinterpret_cast<float (*)[64][8]>(&Vb[0][0][0]);
    if (jhalf == 1) {
        *(f32x4*)&cmb[ws][lane][0] = acc[0];
        *(f32x4*)&cmb[ws][lane][4] = acc[1];
    }
    __syncthreads();
    if (jhalf == 0) {
        f32x4 o0 = acc[0] + *(const f32x4*)&cmb[ws][lane][0];
        f32x4 o1 = acc[1] + *(const f32x4*)&cmb[ws][lane][4];
#pragma unroll
        for (int rr = 0; rr < 4; rr++) {
            int il = strip * 16 + quad * 4 + rr;
            float dnm = fmaxf(denomp[0][whead][il] + denomp[1][whead][il], 1e-30f);
            float v0 = o0[rr] / dnm;
            float v1 = o1[rr] / dnm;
            v0 = v0 > 0.f ? v0 : __expf(v0) - 1.f;
            v1 = v1 > 0.f ? v1 : __expf(v1) - 1.f;
            unsigned oi = (unsigned)(i0 + il) * 512 + hb * 128 + whead * 64 + nn;
            out[oi] = v0;
            out[oi + 16] = v1;
        }
    }
    __syncthreads();
    if (jhalf == 1) {
        *(f32x4*)&cmb[ws][lane][0] = acc[2];
        *(f32x4*)&cmb[ws][lane][4] = acc[3];
    }
    __syncthreads();
    if (jhalf == 0) {
        f32x4 o0 = acc[2] + *(const f32x4*)&cmb[ws][lane][0];
        f32x4 o1 = acc[3] + *(const f32x4*)&cmb[ws][lane][4];
#pragma unroll
        for (int rr = 0; rr < 4; rr++) {
            int il = strip * 16 + quad * 4 + rr;
            float dnm = fmaxf(denomp[0][whead][il] + denomp[1][whead][il], 1e-30f);
            float v0 = o0[rr] / dnm;
            float v1 = o1[rr] / dnm;
            v0 = v0 > 0.f ? v0 : __expf(v0) - 1.f;
            v1 = v1 > 0.f ? v1 : __expf(v1) - 1.f;
            unsigned oi = (unsigned)(i0 + il) * 512 + hb * 128 + whead * 64 + 32 + nn;
            out[oi] = v0;
            out[oi + 16] = v1;
        }
    }
}

extern "C" void kernel_launch(void* const* d_in, const int* in_sizes, int n_in,
                              void* d_out, int out_size, void* d_ws, size_t ws_size,
                              hipStream_t stream) {
    const float* h   = (const float*)d_in[0];   // 4096 x 512 fp32
    const int*   adj = (const int*)d_in[1];     // 4096 x 4096 int32
    const float* W   = (const float*)d_in[2];   // 512 x 512 fp32
    const float* a   = (const float*)d_in[3];   // 128 fp32

    char* ws = (char*)d_ws;
    ushort_t* WhT = (ushort_t*)ws;                           // 4 MB
    ushort_t* WT  = (ushort_t*)(ws + (4u << 20));            // 512 KB
    float* expA = (float*)(ws + (4u << 20) + (512u << 10));  // 4 x 128 KB
    float* expC = expA + 8 * 4096;
    float* expB = expC + 8 * 4096;
    float* expD = expB + 8 * 4096;
    unsigned char* pkm = (unsigned char*)(ws + (5u << 20));  // 2 MB bitmask

    pack_adj<<<1024, 256, 0, stream>>>(adj, pkm);
    transpose_w<<<256, 256, 0, stream>>>(W, WT);
    gemm_whT<<<512, 256, 0, stream>>>(WT, h, a, WhT, expA, expC, expB, expD);
    gat_attn<<<512, 512, 0, stream>>>(pkm, WhT, expA, expC, expB, expD,
                                      (float*)d_out);
}